// Round 9
// baseline (678.976 us; speedup 1.0000x reference)
//
#include <hip/hip_runtime.h>

typedef unsigned short u16;
typedef unsigned int u32;
typedef u16 u16x4 __attribute__((ext_vector_type(4)));
typedef u16 u16x8 __attribute__((ext_vector_type(8)));
typedef __bf16 bf16x4 __attribute__((ext_vector_type(4)));
typedef __bf16 bf16x8 __attribute__((ext_vector_type(8)));
typedef float f32x4 __attribute__((ext_vector_type(4)));
typedef u32 u32x4 __attribute__((ext_vector_type(4)));

#define DEV static __device__ __forceinline__

DEV float b2f(u16 u){ u32 v = (u32)u << 16; return __builtin_bit_cast(float, v); }
DEV u16 f2bu(float f){ u32 x = __builtin_bit_cast(u32, f); u32 r = (x + 0x7FFFu + ((x >> 16) & 1u)) >> 16; return (u16)r; }

DEV f32x4 mfma16(bf16x8 a, bf16x8 b, f32x4 c){
  return __builtin_amdgcn_mfma_f32_16x16x32_bf16(a, b, c, 0, 0, 0);
}

// ---------- diagnostics: clean NaN/Inf/|v|>=2^14, stage markers ----------
__global__ __launch_bounds__(256) void scrub_k(u16* __restrict__ buf, long n, u32* __restrict__ cnt){
  long i = ((long)blockIdx.x * 256 + threadIdx.x) * 8;
  const long stride = (long)gridDim.x * 256 * 8;
  for (; i < n; i += stride){
    u16x8 v = *(u16x8*)(buf + i);
    bool bad = false;
#pragma unroll
    for (int j = 0; j < 8; ++j){
      u32 e = ((u32)v[j] >> 7) & 0xFFu;
      if (e >= 0x8Du){ v[j] = 0; bad = true; }
    }
    if (bad){ *(u16x8*)(buf + i) = v; atomicAdd(cnt, 1u); }
  }
}
__global__ __launch_bounds__(256) void scrub_f32_k(float* __restrict__ buf, long n, u32* __restrict__ cnt){
  long i = ((long)blockIdx.x * 256 + threadIdx.x) * 4;
  const long stride = (long)gridDim.x * 256 * 4;
  for (; i < n; i += stride){
    u32x4 v = *(u32x4*)(buf + i);
    bool bad = false;
#pragma unroll
    for (int j = 0; j < 4; ++j){
      u32 e = (v[j] >> 23) & 0xFFu;
      if (e >= 0x8Du){ v[j] = 0; bad = true; }
    }
    if (bad){ *(u32x4*)(buf + i) = v; atomicAdd(cnt, 1u); }
  }
}
__global__ void report_k(const u32* __restrict__ cnt, float* __restrict__ out, float marker){
  if (*cnt != 0u) out[threadIdx.x] = marker;
}

// ---------- repack fp32 Wq/Wk/Wv -> bf16 W' [1024][3072], fp32 biases -> [3072] ----------
__global__ __launch_bounds__(256) void repack_k(const float* __restrict__ Wq, const float* __restrict__ Wk,
                                                const float* __restrict__ Wv, const float* __restrict__ bq,
                                                const float* __restrict__ bk, const float* __restrict__ bv,
                                                u16* __restrict__ W, float* __restrict__ bias){
  const int idx = blockIdx.x * 256 + threadIdx.x;
  const int n = (idx % 768) * 4;
  const int k = idx / 768;
  const int p = n >> 10, hh = (n >> 6) & 15, d = n & 63;
  const float* src = (p == 0) ? Wq : (p == 1) ? Wk : Wv;
  f32x4 v = *(const f32x4*)(src + hh * 65536 + k * 64 + d);
  u16x4 o;
#pragma unroll
  for (int j = 0; j < 4; ++j) o[j] = f2bu(v[j]);
  *(u16x4*)(W + (long)k * 3072 + n) = o;
  if (idx < 768){
    const float* bs = (p == 0) ? bq : (p == 1) ? bk : bv;
    *(f32x4*)(bias + n) = *(const f32x4*)(bs + hh * 64 + d);
  }
}

// ---------- LayerNorm row 1024 -> bf16. INF32: input fp32, else bf16 ----------
template<int INF32>
__global__ __launch_bounds__(256) void ln_k(const void* __restrict__ xin, const float* __restrict__ gw,
                                            const float* __restrict__ bw, u16* __restrict__ out){
  const int row = blockIdx.x, t = threadIdx.x;
  float f0, f1, f2, f3;
  if (INF32){
    f32x4 v = *(const f32x4*)((const float*)xin + (long)row * 1024 + t * 4);
    f0 = v[0]; f1 = v[1]; f2 = v[2]; f3 = v[3];
  } else {
    u16x4 v = *(const u16x4*)((const u16*)xin + (long)row * 1024 + t * 4);
    f0 = b2f(v[0]); f1 = b2f(v[1]); f2 = b2f(v[2]); f3 = b2f(v[3]);
  }
  float s = f0 + f1 + f2 + f3;
  float s2 = f0 * f0 + f1 * f1 + f2 * f2 + f3 * f3;
#pragma unroll
  for (int m = 1; m < 64; m <<= 1){ s += __shfl_xor(s, m); s2 += __shfl_xor(s2, m); }
  __shared__ float red[8];
  const int w = t >> 6;
  if ((t & 63) == 0){ red[w] = s; red[4 + w] = s2; }
  __syncthreads();
  s = red[0] + red[1] + red[2] + red[3];
  s2 = red[4] + red[5] + red[6] + red[7];
  const float mu = s * (1.f / 1024.f);
  const float rs = rsqrtf(s2 * (1.f / 1024.f) - mu * mu + 1e-5f);
  f32x4 gv = *(const f32x4*)(gw + t * 4);
  f32x4 bv = *(const f32x4*)(bw + t * 4);
  u16x4 ov;
  ov[0] = f2bu((f0 - mu) * rs * gv[0] + bv[0]);
  ov[1] = f2bu((f1 - mu) * rs * gv[1] + bv[1]);
  ov[2] = f2bu((f2 - mu) * rs * gv[2] + bv[2]);
  ov[3] = f2bu((f3 - mu) * rs * gv[3] + bv[3]);
  *(u16x4*)(out + (long)row * 1024 + t * 4) = ov;
}

// ---------- GEMM: C = A(bf16) @ B + bias(fp32). BF32: B is fp32 (convert in staging) else bf16.
// EPI 0: out bf16. 1: +fp32 res, out bf16. 2: GELU, out bf16. 3: +bf16 res, out fp32. ----------
template<int EPI, int BF32>
__global__ __launch_bounds__(256) void gemm_k(const u16* __restrict__ A, const void* __restrict__ Bv,
                                              const float* __restrict__ bias, const void* __restrict__ resv,
                                              void* __restrict__ Cv, int M, int N, int K){
  __shared__ __align__(16) u16 Asm[128 * 40];
  __shared__ __align__(16) u16 Bsm[128 * 40];
  const int t = threadIdx.x, lane = t & 63, w = t >> 6;
  const int g = lane >> 4, qr = lane & 15;
  const int nb = N >> 7;
  const int bm0 = (blockIdx.x / nb) << 7;
  const int bn0 = (blockIdx.x % nb) << 7;
  const int wm = (w >> 1) << 6, wn = (w & 1) << 6;
  const int am = t & 127, akh = (t >> 7) << 4;
  const int bk_ = t & 15, bnc = (t >> 4) << 3;
  f32x4 acc[4][4] = {};
  const u16* Ap = A + (long)(bm0 + am) * K + akh;
  const float* Bpf = (const float*)Bv + bn0 + bnc + (long)bk_ * N;
  const u16*   Bpb = (const u16*)Bv + bn0 + bnc + (long)bk_ * N;
  for (int kt = 0; kt < K; kt += 32){
    u16x8 a0 = *(const u16x8*)(Ap + kt);
    u16x8 a1 = *(const u16x8*)(Ap + kt + 8);
    f32x4 b0a, b0b, b1a, b1b;
    u16x8 c0, c1;
    if (BF32){
      b0a = *(const f32x4*)(Bpf + (long)kt * N);
      b0b = *(const f32x4*)(Bpf + (long)kt * N + 4);
      b1a = *(const f32x4*)(Bpf + (long)(kt + 16) * N);
      b1b = *(const f32x4*)(Bpf + (long)(kt + 16) * N + 4);
    } else {
      c0 = *(const u16x8*)(Bpb + (long)kt * N);
      c1 = *(const u16x8*)(Bpb + (long)(kt + 16) * N);
    }
    __syncthreads();
    *(u16x8*)(Asm + am * 40 + akh) = a0;
    *(u16x8*)(Asm + am * 40 + akh + 8) = a1;
    if (BF32){
#pragma unroll
      for (int j = 0; j < 4; ++j){
        Bsm[(bnc + j) * 40 + bk_]          = f2bu(b0a[j]);
        Bsm[(bnc + 4 + j) * 40 + bk_]      = f2bu(b0b[j]);
        Bsm[(bnc + j) * 40 + bk_ + 16]     = f2bu(b1a[j]);
        Bsm[(bnc + 4 + j) * 40 + bk_ + 16] = f2bu(b1b[j]);
      }
    } else {
#pragma unroll
      for (int j = 0; j < 8; ++j){
        Bsm[(bnc + j) * 40 + bk_]      = c0[j];
        Bsm[(bnc + j) * 40 + bk_ + 16] = c1[j];
      }
    }
    __syncthreads();
    bf16x8 af[4], bf[4];
#pragma unroll
    for (int i = 0; i < 4; ++i) af[i] = *(const bf16x8*)(Asm + (wm + 16 * i + qr) * 40 + 8 * g);
#pragma unroll
    for (int j = 0; j < 4; ++j) bf[j] = *(const bf16x8*)(Bsm + (wn + 16 * j + qr) * 40 + 8 * g);
#pragma unroll
    for (int i = 0; i < 4; ++i)
#pragma unroll
      for (int j = 0; j < 4; ++j)
        acc[i][j] = mfma16(af[i], bf[j], acc[i][j]);
  }
#pragma unroll
  for (int i = 0; i < 4; ++i){
    const int m = bm0 + wm + 16 * i + 4 * g;
#pragma unroll
    for (int j = 0; j < 4; ++j){
      const int n = bn0 + wn + 16 * j + qr;
      const float bb = bias[n];
#pragma unroll
      for (int r = 0; r < 4; ++r){
        float v = acc[i][j][r] + bb;
        if (EPI == 1) v += ((const float*)resv)[(long)(m + r) * N + n];
        if (EPI == 2) v = 0.5f * v * (1.0f + erff(v * 0.70710678f));
        if (EPI == 3) v += b2f(((const u16*)resv)[(long)(m + r) * N + n]);
        if (EPI == 3) ((float*)Cv)[(long)(m + r) * N + n] = v;
        else          ((u16*)Cv)[(long)(m + r) * N + n] = f2bu(v);
      }
    }
  }
}

// ---------- Flash attention (S^T = K Q^T), qkv bf16 ----------
__global__ __launch_bounds__(256) void attn_k(const u16* __restrict__ qkv, u16* __restrict__ o){
  __shared__ __align__(16) unsigned char sm[8192 + 8192 + 4 * 2304];
  const int t = threadIdx.x, lane = t & 63, w = t >> 6;
  const int g = lane >> 4, qr = lane & 15;
  const int bid = blockIdx.x;
  const int qt = bid & 31, hh = (bid >> 5) & 15, b = bid >> 9;
  unsigned char* Ksm = sm;
  unsigned char* Vsm = sm + 8192;
  unsigned char* Psm = sm + 16384 + w * 2304;

  const long tokb = (long)b * 2048;
  const int qrow = qt * 64 + w * 16 + qr;
  const u16* qp = qkv + (tokb + qrow) * 3072 + hh * 64 + 8 * g;
  bf16x8 qf0 = *(const bf16x8*)(qp);
  bf16x8 qf1 = *(const bf16x8*)(qp + 32);

  float m_run = -1e30f, l_run = 0.f;
  f32x4 oacc[4] = {};

  const int skk = t & 63, sch = t >> 6;
  const u16* kb = qkv + tokb * 3072 + 1024 + hh * 64 + sch * 16;
  const u16* vb = qkv + tokb * 3072 + 2048 + hh * 64 + sch * 16;
  const float SC = 0.125f * 1.44269504f;

  for (int kt = 0; kt < 32; ++kt){
    const long rk = (long)(kt * 64 + skk) * 3072;
    u16x8 kv0 = *(const u16x8*)(kb + rk);
    u16x8 kv1 = *(const u16x8*)(kb + rk + 8);
    u16x8 vv0 = *(const u16x8*)(vb + rk);
    u16x8 vv1 = *(const u16x8*)(vb + rk + 8);
    __syncthreads();
    const int ksw = (skk & 7) << 4;
    *(u16x8*)(Ksm + skk * 128 + ((sch * 32) ^ ksw)) = kv0;
    *(u16x8*)(Ksm + skk * 128 + ((sch * 32 + 16) ^ ksw)) = kv1;
#pragma unroll
    for (int j = 0; j < 8; ++j){
      const int d0 = sch * 16 + j, d1 = d0 + 8;
      *(u16*)(Vsm + d0 * 128 + ((skk * 2) ^ ((d0 & 7) << 4))) = vv0[j];
      *(u16*)(Vsm + d1 * 128 + ((skk * 2) ^ ((d1 & 7) << 4))) = vv1[j];
    }
    __syncthreads();

    f32x4 st[4];
#pragma unroll
    for (int c = 0; c < 4; ++c){
      const int kr = c * 16 + qr; const int sw = (kr & 7) << 4;
      bf16x8 k0 = *(const bf16x8*)(Ksm + kr * 128 + ((16 * g) ^ sw));
      bf16x8 k1 = *(const bf16x8*)(Ksm + kr * 128 + ((64 + 16 * g) ^ sw));
      f32x4 s = {};
      s = mfma16(k0, qf0, s);
      s = mfma16(k1, qf1, s);
      st[c] = s;
    }
    float mx = -1e30f;
#pragma unroll
    for (int c = 0; c < 4; ++c)
#pragma unroll
      for (int r = 0; r < 4; ++r){ st[c][r] *= SC; mx = fmaxf(mx, st[c][r]); }
    mx = fmaxf(mx, __shfl_xor(mx, 16));
    mx = fmaxf(mx, __shfl_xor(mx, 32));
    const float mnew = fmaxf(m_run, mx);
    const float alpha = exp2f(m_run - mnew);
    float p[4][4]; float ls = 0.f;
#pragma unroll
    for (int c = 0; c < 4; ++c)
#pragma unroll
      for (int r = 0; r < 4; ++r){ p[c][r] = exp2f(st[c][r] - mnew); ls += p[c][r]; }
    ls += __shfl_xor(ls, 16);
    ls += __shfl_xor(ls, 32);
    l_run = l_run * alpha + ls;
    m_run = mnew;
#pragma unroll
    for (int c = 0; c < 4; ++c) oacc[c] *= alpha;
#pragma unroll
    for (int c = 0; c < 4; ++c){
      u16x4 pw;
#pragma unroll
      for (int r = 0; r < 4; ++r) pw[r] = f2bu(p[c][r]);
      *(bf16x4*)(Psm + qr * 144 + (c * 16 + 4 * g) * 2) = __builtin_bit_cast(bf16x4, pw);
    }
    __syncthreads();
    bf16x8 pb0 = *(const bf16x8*)(Psm + qr * 144 + 16 * g);
    bf16x8 pb1 = *(const bf16x8*)(Psm + qr * 144 + 64 + 16 * g);
#pragma unroll
    for (int c = 0; c < 4; ++c){
      const int dr = c * 16 + qr; const int sw = (dr & 7) << 4;
      bf16x8 v0 = *(const bf16x8*)(Vsm + dr * 128 + ((16 * g) ^ sw));
      bf16x8 v1 = *(const bf16x8*)(Vsm + dr * 128 + ((64 + 16 * g) ^ sw));
      oacc[c] = mfma16(v0, pb0, oacc[c]);
      oacc[c] = mfma16(v1, pb1, oacc[c]);
    }
  }
  __syncthreads();
  const float rl = 1.0f / l_run;
  u16* Osm = (u16*)sm;
#pragma unroll
  for (int c = 0; c < 4; ++c)
#pragma unroll
    for (int r = 0; r < 4; ++r)
      Osm[(w * 16 + qr) * 72 + c * 16 + 4 * g + r] = f2bu(oacc[c][r] * rl);
  __syncthreads();
  const int q_ = t >> 2, dc = t & 3;
  u16x8 o0 = *(const u16x8*)(Osm + q_ * 72 + dc * 16);
  u16x8 o1 = *(const u16x8*)(Osm + q_ * 72 + dc * 16 + 8);
  u16* op = o + (tokb + qt * 64 + q_) * 1024 + hh * 64 + dc * 16;
  *(u16x8*)(op) = o0;
  *(u16x8*)(op + 8) = o1;
}

// ---------- launcher ----------
extern "C" void kernel_launch(void* const* d_in, const int* in_sizes, int n_in,
                              void* d_out, int out_size, void* d_ws, size_t ws_size,
                              hipStream_t stream) {
  const float* x    = (const float*)d_in[0];
  const float* Wq   = (const float*)d_in[1];
  const float* bq   = (const float*)d_in[2];
  const float* Wk   = (const float*)d_in[3];
  const float* bk   = (const float*)d_in[4];
  const float* Wv   = (const float*)d_in[5];
  const float* bv   = (const float*)d_in[6];
  const float* Wo   = (const float*)d_in[7];
  const float* bo   = (const float*)d_in[8];
  const float* ln1g = (const float*)d_in[9];
  const float* ln1b = (const float*)d_in[10];
  const float* ln2g = (const float*)d_in[11];
  const float* ln2b = (const float*)d_in[12];
  const float* W1   = (const float*)d_in[13];
  const float* b1   = (const float*)d_in[14];
  const float* W2   = (const float*)d_in[15];
  const float* b2   = (const float*)d_in[16];
  float* out = (float*)d_out;

  // ws layout — all inside the 52 MB region proven mapped (rounds 2/7):
  //   [0, 8M)      hbuf bf16: h -> o_attn -> h2
  //   [8.5M,16.5M) x2   bf16
  //   [17M, 41M)   qkv  bf16 (dead after attn_k)
  //   [17M, 49M)   ff1  bf16 (written after qkv dead)
  //   [42M, 48M)   wqkv bf16 (dead after gemm<0,0>; aliases only ff1)
  //   [50M)        bqkv fp32 12KB (dead after gemm<0,0>)
  //   [52M)        stage counters
  char* ws = (char*)d_ws;
  u16*   hbuf = (u16*)(ws);
  u16*   x2   = (u16*)(ws + (8l << 20) + (1l << 19));
  u16*   qkv  = (u16*)(ws + (17l << 20));
  u16*   ff1  = (u16*)(ws + (17l << 20));
  u16*   wqkv = (u16*)(ws + (42l << 20));
  float* bqkv = (float*)(ws + (50l << 20));
  u32*   cnt  = (u32*)(ws + (52l << 20));
  u16*   oat  = hbuf;
  u16*   h2   = hbuf;

  hipMemsetAsync(cnt, 0, 32, stream);

  repack_k<<<3072, 256, 0, stream>>>(Wq, Wk, Wv, bq, bk, bv, wqkv, bqkv);
  ln_k<1><<<4096, 256, 0, stream>>>(x, ln1g, ln1b, hbuf);
  scrub_k<<<2048, 256, 0, stream>>>(hbuf, 4194304l, cnt + 0);
  gemm_k<0, 0><<<(4096 / 128) * (3072 / 128), 256, 0, stream>>>(hbuf, wqkv, bqkv, nullptr, qkv, 4096, 3072, 1024);
  scrub_k<<<2048, 256, 0, stream>>>(qkv, 12582912l, cnt + 1);
  attn_k<<<1024, 256, 0, stream>>>(qkv, oat);
  scrub_k<<<2048, 256, 0, stream>>>(oat, 4194304l, cnt + 2);
  gemm_k<1, 1><<<(4096 / 128) * (1024 / 128), 256, 0, stream>>>(oat, Wo, bo, x, x2, 4096, 1024, 1024);
  scrub_k<<<2048, 256, 0, stream>>>(x2, 4194304l, cnt + 3);
  ln_k<0><<<4096, 256, 0, stream>>>(x2, ln2g, ln2b, h2);
  scrub_k<<<2048, 256, 0, stream>>>(h2, 4194304l, cnt + 4);
  gemm_k<2, 1><<<(4096 / 128) * (4096 / 128), 256, 0, stream>>>(h2, W1, b1, nullptr, ff1, 4096, 4096, 1024);
  scrub_k<<<2048, 256, 0, stream>>>(ff1, 16777216l, cnt + 5);
  gemm_k<3, 1><<<(4096 / 128) * (1024 / 128), 256, 0, stream>>>(ff1, W2, b2, x2, out, 4096, 1024, 4096);
  scrub_f32_k<<<2048, 256, 0, stream>>>(out, 4194304l, cnt + 6);

  report_k<<<1, 64, 0, stream>>>(cnt + 6, out, 700.0f);
  report_k<<<1, 64, 0, stream>>>(cnt + 5, out, 600.0f);
  report_k<<<1, 64, 0, stream>>>(cnt + 4, out, 500.0f);
  report_k<<<1, 64, 0, stream>>>(cnt + 3, out, 400.0f);
  report_k<<<1, 64, 0, stream>>>(cnt + 2, out, 300.0f);
  report_k<<<1, 64, 0, stream>>>(cnt + 1, out, 200.0f);
  report_k<<<1, 64, 0, stream>>>(cnt + 0, out, 100.0f);
}